// Round 1
// baseline (373.789 us; speedup 1.0000x reference)
//
#include <hip/hip_runtime.h>
#include <math.h>

typedef unsigned short u16;
typedef __attribute__((ext_vector_type(8))) short s8v;
typedef __attribute__((ext_vector_type(4))) float f4v;

#define BH 16
#define SEQ 4096
#define DD 128

__device__ __forceinline__ float b2f(u16 h){ union{unsigned u; float f;} v; v.u=((unsigned)h)<<16; return v.f; }
__device__ __forceinline__ u16 f2b(float f){ union{float f; unsigned u;} v; v.f=f; unsigned r=v.u+0x7FFFu+((v.u>>16)&1u); return (u16)(r>>16); }
__device__ __forceinline__ f4v mm16(s8v a, s8v b, f4v c){ return __builtin_amdgcn_mfma_f32_16x16x32_bf16(a,b,c,0,0,0); }
__device__ __forceinline__ float dot4(float4 a, float4 b){ return a.x*b.x+a.y*b.y+a.z*b.z+a.w*b.w; }
// LDS-only barrier: p2's cross-wave traffic is LDS-only; global loads are
// lane-private, so no vmcnt drain needed -> prefetches stay in flight.
__device__ __forceinline__ void bar_lds(){
  asm volatile("s_waitcnt lgkmcnt(0)\n\ts_barrier" ::: "memory");
}

// ---------------------------------------------------------------------------
// Phase 1 (c=32) per chunk: T=(I-strictlower(kb kn^T))^-1, AL=trilincl(qn kn^T),
// w=T kb, u0=T vb, qen=AL w - qn, p=AL u0.  Also emits knT (bf16, [d][token]).
// ---------------------------------------------------------------------------
__global__ __launch_bounds__(512,4) void p1_kernel(
    const float* __restrict__ gq, const float* __restrict__ gk,
    const float* __restrict__ gv, const float* __restrict__ gbeta,
    u16* __restrict__ gw, u16* __restrict__ gqen, u16* __restrict__ gu0,
    u16* __restrict__ gknT, float* __restrict__ gik, float* __restrict__ gout)
{
  __shared__ u16 qnh[32][136], qnl[32][136];
  __shared__ u16 arena1[10240];
  __shared__ u16 vbT[128][40], kbT[128][40];
  __shared__ u16 arena2[8704];
  __shared__ float Amat[32][33];
  __shared__ float bet[32];

  u16 (*knh)[136] = (u16(*)[136])arena1;
  u16 (*knl)[136] = (u16(*)[136])(arena1+4352);
  u16 (*wTT)[40]  = (u16(*)[40])arena1;
  u16 (*u0T)[40]  = (u16(*)[40])(arena1+5120);
  u16 (*vb16)[136]= (u16(*)[136])arena2;
  u16 (*kb16)[136]= (u16(*)[136])(arena2+4352);
  u16 (*Tb)[40]   = (u16(*)[40])arena2;
  u16 (*ALb)[40]  = (u16(*)[40])(arena2+1280);

  const int cid = blockIdx.x, bh = cid>>7, ci = cid&127;
  const int t = threadIdx.x, wave = t>>6, lane = t&63, m = lane&15, qq = lane>>4;
  const size_t tokbase = (size_t)bh*SEQ + (size_t)ci*32;
  const size_t base = tokbase*DD;

  for (int p=0;p<2;++p){
    int idx = t + (p<<9);
    int r = idx>>5, c4 = (idx&31)<<2;
    float4 qv = *(const float4*)(gq + base + r*DD + c4);
    float4 kv = *(const float4*)(gk + base + r*DD + c4);
    float4 vv = *(const float4*)(gv + base + r*DD + c4);
    float nq = dot4(qv,qv), nk = dot4(kv,kv);
    nq += __shfl_xor(nq,1); nq += __shfl_xor(nq,2); nq += __shfl_xor(nq,4);
    nq += __shfl_xor(nq,8); nq += __shfl_xor(nq,16);
    nk += __shfl_xor(nk,1); nk += __shfl_xor(nk,2); nk += __shfl_xor(nk,4);
    nk += __shfl_xor(nk,8); nk += __shfl_xor(nk,16);
    float iq = 1.f/sqrtf(nq+1e-6f), ik = 1.f/sqrtf(nk+1e-6f);
    float bb = gbeta[tokbase + r];
    if ((idx&31)==0){ gik[tokbase+r]=ik; bet[r]=bb; }
    float qa[4]={qv.x,qv.y,qv.z,qv.w}, ka[4]={kv.x,kv.y,kv.z,kv.w}, va[4]={vv.x,vv.y,vv.z,vv.w};
    union{u16 s[4]; uint2 v;} hq,lq,hk,lk,sv,sb;
    #pragma unroll
    for(int i=0;i<4;++i){
      float qn = qa[i]*iq; u16 h1=f2b(qn); hq.s[i]=h1; lq.s[i]=f2b(qn-b2f(h1));
      float kn = ka[i]*ik; u16 h2=f2b(kn); hk.s[i]=h2; lk.s[i]=f2b(kn-b2f(h2));
      sv.s[i]=f2b(va[i]*bb); sb.s[i]=f2b(kn*bb);
    }
    *(uint2*)&qnh[r][c4]=hq.v; *(uint2*)&qnl[r][c4]=lq.v;
    *(uint2*)&knh[r][c4]=hk.v; *(uint2*)&knl[r][c4]=lk.v;
    *(uint2*)&vb16[r][c4]=sv.v; *(uint2*)&kb16[r][c4]=sb.v;
  }
  __syncthreads();

  {
    u16* kdst = gknT + ((size_t)(bh*32 + (ci>>2)))*16384 + (size_t)((ci&3)*32);
    for (int g=0; g<2; ++g){
      int tau = t + (g<<9);
      int r = tau & 31, d0 = (tau>>5)<<2;
      union{u16 s[4]; uint2 v;} vv, kk, kn4;
      vv.v  = *(uint2*)&vb16[r][d0];
      kk.v  = *(uint2*)&kb16[r][d0];
      kn4.v = *(uint2*)&knh[r][d0];
      #pragma unroll
      for(int i=0;i<4;++i){
        vbT[d0+i][r] = vv.s[i];
        kbT[d0+i][r] = kk.s[i];
        kdst[(size_t)(d0+i)*128 + r] = kn4.s[i];
      }
    }
  }
  __syncthreads();

  {
    const int TI[3]={0,1,1}, TJ[3]={0,0,1};
    if (wave < 3){
      int ti=TI[wave], tj=TJ[wave];
      f4v acc = {0.f,0.f,0.f,0.f};
      #pragma unroll
      for(int kc=0;kc<4;++kc){
        int ko = kc*32 + qq*8;
        s8v ah = *(const s8v*)&knh[ti*16+m][ko];
        s8v al = *(const s8v*)&knl[ti*16+m][ko];
        s8v bhv = *(const s8v*)&knh[tj*16+m][ko];
        s8v blv = *(const s8v*)&knl[tj*16+m][ko];
        acc = mm16(ah,bhv,acc); acc = mm16(ah,blv,acc); acc = mm16(al,bhv,acc);
      }
      #pragma unroll
      for(int r=0;r<4;++r){
        int row = ti*16+qq*4+r, col = tj*16+m;
        Amat[row][col] = (col<row)? (-bet[row]*acc[r]) : 0.f;
      }
    } else if (wave < 6){
      int ti=TI[wave-3], tj=TJ[wave-3];
      f4v acc = {0.f,0.f,0.f,0.f};
      #pragma unroll
      for(int kc=0;kc<4;++kc){
        int ko = kc*32 + qq*8;
        s8v ah = *(const s8v*)&qnh[ti*16+m][ko];
        s8v al = *(const s8v*)&qnl[ti*16+m][ko];
        s8v bhv = *(const s8v*)&knh[tj*16+m][ko];
        s8v blv = *(const s8v*)&knl[tj*16+m][ko];
        acc = mm16(ah,bhv,acc); acc = mm16(ah,blv,acc); acc = mm16(al,bhv,acc);
      }
      #pragma unroll
      for(int r=0;r<4;++r){
        int row = ti*16+qq*4+r, col = tj*16+m;
        ALb[row][col] = (col<=row)? f2b(acc[r]) : (u16)0;
      }
    } else if (wave == 6){
      #pragma unroll
      for(int r=0;r<4;++r) ALb[qq*4+r][16+m] = (u16)0;
    }
  }
  __syncthreads();

  if (t < 32){
    float a[32];
    #pragma unroll
    for(int i=0;i<32;++i) a[i] = (t<i)? Amat[i][t] : 0.f;
    #pragma unroll
    for(int i=2;i<32;++i){
      float s = a[i];
      #pragma unroll
      for(int j=1;j<i;++j) s += __shfl(a[i],j)*a[j];
      a[i] = s;
    }
    #pragma unroll
    for(int i=0;i<32;++i) Tb[i][t] = f2b(a[i] + (i==t?1.f:0.f));
  }
  __syncthreads();

  #pragma unroll
  for (int q8 = 0; q8 < 4; ++q8){
    int tau = wave + q8*8;
    bool isu = (tau < 16);
    int tile16 = tau & 15, rt = tile16>>3, dt = tile16&7;
    s8v aT = *(const s8v*)&Tb[rt*16+m][qq*8];
    s8v bB = isu ? *(const s8v*)&vbT[dt*16+m][qq*8] : *(const s8v*)&kbT[dt*16+m][qq*8];
    f4v acc = {0.f,0.f,0.f,0.f};
    acc = mm16(aT,bB,acc);
    int tok0 = rt*16 + qq*4, dcol = dt*16+m;
    u16* gdst = isu ? gu0 : gw;
    u16 (*ldst)[40] = isu ? u0T : wTT;
    union{u16 s[4]; uint2 v;} pk;
    #pragma unroll
    for(int r=0;r<4;++r){
      u16 hv = f2b(acc[r]); pk.s[r]=hv;
      gdst[(tokbase + tok0 + r)*DD + dcol] = hv;
    }
    *(uint2*)&ldst[dcol][tok0] = pk.v;
  }
  __syncthreads();

  #pragma unroll
  for (int q8 = 0; q8 < 4; ++q8){
    int tau = wave + q8*8;
    bool isq = (tau < 16);
    int tile16 = tau & 15, rt = tile16>>3, dt = tile16&7;
    s8v aA = *(const s8v*)&ALb[rt*16+m][qq*8];
    s8v bB = isq ? *(const s8v*)&wTT[dt*16+m][qq*8] : *(const s8v*)&u0T[dt*16+m][qq*8];
    f4v acc = {0.f,0.f,0.f,0.f};
    acc = mm16(aA,bB,acc);
    int tok0 = rt*16+qq*4, dcol = dt*16+m;
    #pragma unroll
    for(int r=0;r<4;++r){
      size_t gi = (tokbase+tok0+r)*DD + dcol;
      if (isq){
        float qn = b2f(qnh[tok0+r][dcol]) + b2f(qnl[tok0+r][dcol]);
        gqen[gi] = f2b(acc[r] - qn);
      } else {
        gout[gi] = acc[r];
      }
    }
  }
}

// ---------------------------------------------------------------------------
// merge<C>
// ---------------------------------------------------------------------------
template<int C>
__global__ __launch_bounds__(256) void merge_kernel(
    const float* __restrict__ gk, const float* __restrict__ gik,
    u16* __restrict__ gw, u16* __restrict__ gqen, u16* __restrict__ gu0,
    float* __restrict__ gout)
{
  constexpr int P = 2048 / C;
  constexpr int SM = C + 8;
  __shared__ u16 k1[C][136];
  __shared__ u16 w1T[128][SM], u01T[128][SM];
  __shared__ u16 Mw[C][SM], MG[C][SM];
  const int bh = blockIdx.x / P, pr = blockIdx.x % P;
  const int t = threadIdx.x, wave = t>>6, lane = t&63, m = lane&15, qq = lane>>4;
  const int base1 = pr*2*C, base2 = base1 + C;
  const size_t tb1 = (size_t)bh*SEQ + base1, tb2 = (size_t)bh*SEQ + base2;

  for(int p=0;p<C*32/256;++p){
    int idx = t + (p<<8); int j = idx>>5, c4 = (idx&31)<<2;
    float ik = gik[tb1 + j];
    float4 kv = *(const float4*)(gk + (tb1+j)*DD + c4);
    union{u16 s[4]; uint2 v;} pk;
    pk.s[0]=f2b(kv.x*ik); pk.s[1]=f2b(kv.y*ik); pk.s[2]=f2b(kv.z*ik); pk.s[3]=f2b(kv.w*ik);
    *(uint2*)&k1[j][c4] = pk.v;
  }
  for(int p=0;p<C*16/256;++p){
    int idx = t + (p<<8); int j = idx>>4, d8 = (idx&15)<<3;
    s8v wv = *(const s8v*)(gw + (tb1+j)*DD + d8);
    s8v uv = *(const s8v*)(gu0 + (tb1+j)*DD + d8);
    const u16* wsp = (const u16*)&wv; const u16* usp = (const u16*)&uv;
    for(int i=0;i<8;++i){ w1T[d8+i][j]=wsp[i]; u01T[d8+i][j]=usp[i]; }
  }
  __syncthreads();

  constexpr int NT = (C/16)*(C/16);
  for(int tile = wave; tile < NT; tile += 4){
    int ti = tile/(C/16), tj = tile%(C/16);
    f4v aw = {0.f,0.f,0.f,0.f}, ag = {0.f,0.f,0.f,0.f};
    for(int kc=0;kc<4;++kc){
      int ko = kc*32 + qq*8;
      s8v b  = *(const s8v*)&k1[tj*16+m][ko];
      s8v a1 = *(const s8v*)(gw   + (tb2 + ti*16+m)*DD + ko);
      s8v a2 = *(const s8v*)(gqen + (tb2 + ti*16+m)*DD + ko);
      aw = mm16(a1,b,aw); ag = mm16(a2,b,ag);
    }
    for(int r=0;r<4;++r){
      Mw[ti*16+qq*4+r][tj*16+m] = f2b(aw[r]);
      MG[ti*16+qq*4+r][tj*16+m] = f2b(ag[r]);
    }
  }
  __syncthreads();

  {
    const u16 (*Ma)[SM] = (wave==0||wave==2) ? Mw : MG;
    const u16 (*Bt)[SM] = (wave<2) ? w1T : u01T;
    for(int tile=0; tile<(C/16)*8; ++tile){
      int ti = tile>>3, dt = tile&7;
      f4v acc = {0.f,0.f,0.f,0.f};
      for(int kc=0;kc<C/32;++kc){
        int ko = kc*32+qq*8;
        s8v a = *(const s8v*)&Ma[ti*16+m][ko];
        s8v b = *(const s8v*)&Bt[dt*16+m][ko];
        acc = mm16(a,b,acc);
      }
      int d = dt*16+m;
      for(int r=0;r<4;++r){
        size_t gi = (tb2 + ti*16 + qq*4 + r)*DD + d;
        if (wave==0)      gw[gi]   = f2b(b2f(gw[gi])   - acc[r]);
        else if (wave==1) gqen[gi] = f2b(b2f(gqen[gi]) - acc[r]);
        else if (wave==2) gu0[gi]  = f2b(b2f(gu0[gi])  - acc[r]);
        else              gout[gi] = gout[gi] - acc[r];
      }
    }
  }
}

// ---------------------------------------------------------------------------
// Phase 2: scan over 32 chunks of 128.  u = u0 - w S; o = p - qen S; S += kn^T u.
// Software-pipelined: all global data for step ci+1 prefetched into registers
// during step ci; barriers are LDS-only so prefetch loads stay in flight.
// This round:
//  - __launch_bounds__(512,2): VGPR cap 256 (was 80) so the prefetch actually
//    lives in registers.  Grid is 128 blocks -> 1 block/CU either way, so no
//    occupancy cost.
//  - lSb/lub: stride 128 (0 mod 32 dwords) + row-keyed XOR-16B swizzle
//    (byte ^= (m&7)<<4) on both write and read -> conflict-free b128 reads.
//  - packed uint2 LDS writes (2x ds_write_b64 instead of 8x ds_write_b16).
//  - hi/lo accumulator chains split (4-deep instead of 8-deep dependent MFMA).
// ---------------------------------------------------------------------------
__global__ __launch_bounds__(512,2) void p2_kernel(
    const u16* __restrict__ gw, const u16* __restrict__ gqen,
    const u16* __restrict__ gu0, const u16* __restrict__ knT,
    float* __restrict__ gout)
{
  __shared__ u16 lSb[2][16][128];
  __shared__ u16 lub[2][16][128];
  const int bh = blockIdx.x & 15, slice = blockIdx.x >> 4;
  const int t = threadIdx.x, wave = t>>6, lane = t&63, m = lane&15, qq = lane>>4;
  f4v S = {0.f,0.f,0.f,0.f};
  float* out_o = gout;
  float* out_S = gout + (size_t)BH*SEQ*DD;
  const size_t bhb = (size_t)bh*SEQ;
  const int dv = slice*16 + m;
  const int swz = (m & 7) << 4;        // row-keyed 16B XOR swizzle
  char* rS0 = (char*)&lSb[0][m][0];
  char* rS1 = (char*)&lSb[1][m][0];
  char* rU0 = (char*)&lub[0][m][0];
  char* rU1 = (char*)&lub[1][m][0];

  s8v wf[4], qf[4], kf[4];
  float u0f[4], pf[4];
  // prefetch step 0
  {
    const u16* wbase = gw   + bhb*DD + (size_t)(wave*16+m)*DD;
    const u16* qbase = gqen + bhb*DD + (size_t)(wave*16+m)*DD;
    const u16* ktb   = knT + ((size_t)(bh*32))*16384 + (size_t)(wave*16+m)*DD;
    #pragma unroll
    for(int kc=0;kc<4;++kc){
      wf[kc] = *(const s8v*)(wbase + kc*32 + qq*8);
      qf[kc] = *(const s8v*)(qbase + kc*32 + qq*8);
      kf[kc] = *(const s8v*)(ktb   + kc*32 + qq*8);
    }
    #pragma unroll
    for(int r=0;r<4;++r){
      size_t gi = (bhb + wave*16 + qq*4 + r)*DD + dv;
      u0f[r] = b2f(gu0[gi]);
      pf[r]  = out_o[gi];
    }
  }

  for (int ci = 0; ci < 32; ++ci) {
    // prefetch step ci+1 (wraps harmlessly at the end)
    s8v wn[4], qn4[4], kn4[4];
    float u0n[4], pn[4];
    {
      int cn = (ci + 1) & 31;
      const u16* wbase = gw   + (bhb + (size_t)cn*128)*DD + (size_t)(wave*16+m)*DD;
      const u16* qbase = gqen + (bhb + (size_t)cn*128)*DD + (size_t)(wave*16+m)*DD;
      const u16* ktb   = knT + ((size_t)(bh*32+cn))*16384 + (size_t)(wave*16+m)*DD;
      #pragma unroll
      for(int kc=0;kc<4;++kc){
        wn[kc]  = *(const s8v*)(wbase + kc*32 + qq*8);
        qn4[kc] = *(const s8v*)(qbase + kc*32 + qq*8);
        kn4[kc] = *(const s8v*)(ktb   + kc*32 + qq*8);
      }
      #pragma unroll
      for(int r=0;r<4;++r){
        size_t gi = (bhb + (size_t)cn*128 + wave*16 + qq*4 + r)*DD + dv;
        u0n[r] = b2f(gu0[gi]);
        pn[r]  = out_o[gi];
      }
    }

    // (a) S -> lSb (hi/lo), packed + swizzled
    {
      int d0 = wave*16 + qq*4;
      int bo = (d0*2) ^ swz;
      union{u16 s[4]; uint2 v;} ph, pl;
      #pragma unroll
      for(int r=0;r<4;++r){
        float v = S[r]; u16 hi = f2b(v); ph.s[r]=hi; pl.s[r]=f2b(v - b2f(hi));
      }
      *(uint2*)(rS0 + bo) = ph.v;
      *(uint2*)(rS1 + bo) = pl.v;
    }
    bar_lds();
    // (b) au = w.S, ao = qen.S  (hi/lo chains split: 4-deep each)
    f4v auh = {0.f,0.f,0.f,0.f}, aul = {0.f,0.f,0.f,0.f};
    f4v aoh = {0.f,0.f,0.f,0.f}, aol = {0.f,0.f,0.f,0.f};
    #pragma unroll
    for (int kc = 0; kc < 4; ++kc) {
      int bo = (kc*64 + qq*16) ^ swz;
      s8v bhv = *(const s8v*)(rS0 + bo);
      s8v blv = *(const s8v*)(rS1 + bo);
      auh = mm16(wf[kc],bhv,auh); aul = mm16(wf[kc],blv,aul);
      aoh = mm16(qf[kc],bhv,aoh); aol = mm16(qf[kc],blv,aol);
    }
    // (c) u = u0 - au -> lub (hi/lo, packed+swizzled); o = p - ao -> global
    {
      int j0 = wave*16 + qq*4;
      int bo = (j0*2) ^ swz;
      union{u16 s[4]; uint2 v;} ph, pl;
      #pragma unroll
      for(int r=0;r<4;++r){
        size_t gi = (bhb + (size_t)ci*128 + j0 + r)*DD + dv;
        float uv = u0f[r] - (auh[r] + aul[r]);
        u16 hi = f2b(uv); ph.s[r]=hi; pl.s[r]=f2b(uv - b2f(hi));
        out_o[gi] = pf[r] - (aoh[r] + aol[r]);
      }
      *(uint2*)(rU0 + bo) = ph.v;
      *(uint2*)(rU1 + bo) = pl.v;
    }
    bar_lds();
    // (d) S += kn^T u  (hi into S, lo into separate 4-deep chain, then add)
    f4v Sl = {0.f,0.f,0.f,0.f};
    #pragma unroll
    for (int jc = 0; jc < 4; ++jc) {
      int bo = (jc*64 + qq*16) ^ swz;
      s8v bhv = *(const s8v*)(rU0 + bo);
      s8v blv = *(const s8v*)(rU1 + bo);
      S  = mm16(kf[jc],bhv,S);
      Sl = mm16(kf[jc],blv,Sl);
    }
    S = S + Sl;
    // rotate prefetch
    #pragma unroll
    for(int kc=0;kc<4;++kc){ wf[kc]=wn[kc]; qf[kc]=qn4[kc]; kf[kc]=kn4[kc]; }
    #pragma unroll
    for(int r=0;r<4;++r){ u0f[r]=u0n[r]; pf[r]=pn[r]; }
  }
  {
    int d0 = wave*16 + qq*4;
    #pragma unroll
    for(int r=0;r<4;++r)
      out_S[(size_t)bh*16384 + (size_t)(d0+r)*DD + dv] = S[r];
  }
}

extern "C" void kernel_launch(void* const* d_in, const int* in_sizes, int n_in,
                              void* d_out, int out_size, void* d_ws, size_t ws_size,
                              hipStream_t stream) {
  const float* q    = (const float*)d_in[0];
  const float* k    = (const float*)d_in[1];
  const float* v    = (const float*)d_in[2];
  const float* beta = (const float*)d_in[3];
  u16* wsu  = (u16*)d_ws;
  u16* gw   = wsu;
  u16* gqen = wsu + 8388608;
  u16* gu0  = wsu + 16777216;
  u16* knT  = wsu + 25165824;
  float* gik = (float*)(wsu + 33554432);
  float* out = (float*)d_out;

  p1_kernel<<<dim3(2048), dim3(512), 0, stream>>>(q, k, v, beta, gw, gqen, gu0, knT, gik, out);
  merge_kernel<32><<<dim3(1024), dim3(256), 0, stream>>>(k, gik, gw, gqen, gu0, out);
  merge_kernel<64><<<dim3(512),  dim3(256), 0, stream>>>(k, gik, gw, gqen, gu0, out);
  p2_kernel<<<dim3(128), dim3(512), 0, stream>>>(gw, gqen, gu0, knT, out);
}